// Round 4
// baseline (190.809 us; speedup 1.0000x reference)
//
#include <hip/hip_runtime.h>

// Diversity2: mean(0.3 * pearson_corr(softmax(o1/T), softmax(o2/T), axis=1))
//
// Identities:
//  (1) corr is invariant to per-row positive scaling and shift -> softmax
//      normalization and max-subtraction drop out: corr(p1,p2) ==
//      corr(exp(o1/T), exp(o2/T)).
//  (2) shift again: x = exp(o/T) - 1 (exact Sterbenz subtraction, exp in
//      [0.78,1.32]) centers x near 0 so fp32 accumulation of
//      {Sx,Sy,Sxx,Syy,Sxy} has no catastrophic cancellation. fp64 only in
//      the per-row epilogue and final mean.
//
// Round-4 structure: pure-register streaming (no LDS staging), fully
// unrolled row loads (8 x global_load_dwordx4 = 8 KB/row-pair issued
// back-to-back), explicit depth-2 register pipeline (load row p+1 while
// computing row p; named two-state Ra/Rb, no runtime-indexed arrays).
// ~16-20 waves/CU resident x 8-16 KB in flight each >> latency-BW product.
// 2048 blocks (4 waves, 8 rows/wave): many blocks per resident slot so the
// dispatcher load-balances the L3-hit/HBM-miss block bimodality (round 3's
// one-round 512-block grid pinned completion to the slow HBM blocks: -16%).
// Fused finish: block partial -> ws, release-increment counter, last block
// reduces all 2048 partials (counter zeroed per launch via 4B memsetAsync).
//
// Tail: row = 1000 floats = 250 float4. Chunk k reads float4 index
// 64k+lane, valid for k<3 always, k=3 only lanes<58. Lanes >=58 read index 0
// (row start, always in-bounds, no branch) and their inputs are zeroed at
// consume: exp(0)-1 == 0 contributes nothing to any sum.

#define N_ROWS  65536
#define N_C     1000
#define NBLOCKS 2048
#define WPB     4
#define RPW     8           // 65536 / (2048*4)

struct RowRegs { float4 a0, a1, a2, a3, b0, b1, b2, b3; };

__device__ __forceinline__ void load_row(const float* __restrict__ o1,
                                         const float* __restrict__ o2,
                                         long row, int lane, int i3,
                                         RowRegs& R) {
    const float4* A = reinterpret_cast<const float4*>(o1 + row * (long)N_C);
    const float4* B = reinterpret_cast<const float4*>(o2 + row * (long)N_C);
    R.a0 = A[lane]; R.a1 = A[64 + lane]; R.a2 = A[128 + lane]; R.a3 = A[i3];
    R.b0 = B[lane]; R.b1 = B[64 + lane]; R.b2 = B[128 + lane]; R.b3 = B[i3];
}

__device__ __forceinline__ double row_cost(const RowRegs& R, int lane) {
    constexpr float INV_T = 1.0f / 20.0f;
    float sx = 0.f, sy = 0.f, sxx = 0.f, syy = 0.f, sxy = 0.f;
    auto acc4 = [&](float4 a, float4 b, bool ok) {
        float av[4] = {a.x, a.y, a.z, a.w};
        float bv[4] = {b.x, b.y, b.z, b.w};
        #pragma unroll
        for (int e = 0; e < 4; ++e) {
            float va = ok ? av[e] : 0.0f;
            float vb = ok ? bv[e] : 0.0f;
            float x = __expf(va * INV_T) - 1.0f;
            float y = __expf(vb * INV_T) - 1.0f;
            sx += x;  sy += y;
            sxx = fmaf(x, x, sxx);
            syy = fmaf(y, y, syy);
            sxy = fmaf(x, y, sxy);
        }
    };
    acc4(R.a0, R.b0, true);
    acc4(R.a1, R.b1, true);
    acc4(R.a2, R.b2, true);
    acc4(R.a3, R.b3, lane < 58);
    #pragma unroll
    for (int off = 32; off; off >>= 1) {
        sx  += __shfl_xor(sx,  off, 64);
        sy  += __shfl_xor(sy,  off, 64);
        sxx += __shfl_xor(sxx, off, 64);
        syy += __shfl_xor(syy, off, 64);
        sxy += __shfl_xor(sxy, off, 64);
    }
    constexpr double invC = 1.0 / (double)N_C;
    double dx = (double)sx, dy = (double)sy;
    double num = (double)sxy - dx * dy * invC;
    double vx  = (double)sxx - dx * dx * invC;
    double vy  = (double)syy - dy * dy * invC;
    return num / sqrt(vx * vy);
}

__global__ __launch_bounds__(256) void div2_fused(
        const float* __restrict__ o1, const float* __restrict__ o2,
        double* __restrict__ ws, unsigned int* __restrict__ cnt,
        float* __restrict__ out) {
    __shared__ double dred[WPB];
    __shared__ int slast;

    const int wave = threadIdx.x >> 6;
    const int lane = threadIdx.x & 63;
    const int gw   = blockIdx.x * WPB + wave;
    const long r0  = (long)gw * RPW;
    const int  i3  = (lane < 58) ? (192 + lane) : 0;   // clamped chunk-3 idx

    RowRegs Ra, Rb;
    load_row(o1, o2, r0, lane, i3, Ra);

    double acc = 0.0;
    #pragma unroll 1
    for (int p = 0; p < RPW; p += 2) {
        load_row(o1, o2, r0 + p + 1, lane, i3, Rb);   // prefetch odd row
        acc += row_cost(Ra, lane);
        if (p + 2 < RPW)
            load_row(o1, o2, r0 + p + 2, lane, i3, Ra);  // prefetch even row
        acc += row_cost(Rb, lane);
    }

    // ---- block combine ----
    if (lane == 0) dred[wave] = acc;
    __syncthreads();
    if (threadIdx.x == 0) {
        ws[blockIdx.x] = dred[0] + dred[1] + dred[2] + dred[3];
        unsigned int old = __hip_atomic_fetch_add(cnt, 1u, __ATOMIC_ACQ_REL,
                                                  __HIP_MEMORY_SCOPE_AGENT);
        slast = (old == NBLOCKS - 1);
    }
    __syncthreads();

    // ---- last finishing block: reduce all 2048 partials ----
    if (slast) {
        const int t = threadIdx.x;
        double s = 0.0;
        #pragma unroll
        for (int i = 0; i < NBLOCKS / 256; ++i)
            s += __hip_atomic_load(&ws[t + i * 256], __ATOMIC_RELAXED,
                                   __HIP_MEMORY_SCOPE_AGENT);
        #pragma unroll
        for (int off = 32; off; off >>= 1) s += __shfl_xor(s, off, 64);
        if (lane == 0) dred[wave] = s;
        __syncthreads();
        if (t == 0)
            out[0] = (float)((dred[0] + dred[1] + dred[2] + dred[3]) *
                             (0.3 / (double)N_ROWS));
    }
}

extern "C" void kernel_launch(void* const* d_in, const int* in_sizes, int n_in,
                              void* d_out, int out_size, void* d_ws, size_t ws_size,
                              hipStream_t stream) {
    const float* o1 = (const float*)d_in[0];
    const float* o2 = (const float*)d_in[1];
    // d_in[2] (targets) is unused by the reference.
    float* out = (float*)d_out;
    double* ws = (double*)d_ws;                        // 2048 block partials
    unsigned int* cnt = (unsigned int*)((char*)d_ws + NBLOCKS * sizeof(double));

    // zero the completion counter each call (graph-capturable async memset)
    hipMemsetAsync((void*)cnt, 0, sizeof(unsigned int), stream);

    div2_fused<<<NBLOCKS, 256, 0, stream>>>(o1, o2, ws, cnt, out);
}

// Round 5
// 100.346 us; speedup vs baseline: 1.9015x; 1.9015x over previous
//
#include <hip/hip_runtime.h>

// Diversity2: mean(0.3 * pearson_corr(softmax(o1/T), softmax(o2/T), axis=1))
//
// Identities:
//  (1) corr is invariant to per-row positive scaling and shift -> softmax
//      normalization and max-subtraction drop out: corr(p1,p2) ==
//      corr(exp(o1/T), exp(o2/T)).
//  (2) shift again: x = exp(o/T) - 1 (exact Sterbenz subtraction, exp in
//      [0.78,1.32]) centers x near 0 so fp32 accumulation of
//      {Sx,Sy,Sxx,Syy,Sxy} has no catastrophic cancellation
//      (Sxx ~ 2.5 vs (Sx)^2/C ~ 0.003). fp64 only in the per-row epilogue
//      and the final mean.
//
// Round-5 structure: EXACTLY round 1's proven shape (best: 100.7 us) --
// grid-stride rows, 2048 blocks x 4 waves, one row in registers at a time,
// separate tiny stage-2 kernel -- with two targeted deltas:
//   (a) fp32 inner accumulation instead of fp64 (halves VALU, 30 instead of
//       60 shuffle ops per row),
//   (b) row fully unrolled: all 8 global_load_dwordx4 (one row-pair, 8 KB)
//       issue back-to-back before any use (r1's dynamic-trip loop kept only
//       ~2 in flight). Single-row live set ~60 VGPR -> occupancy stays ~8
//       waves/SIMD (r4's failure was 2-row live set + struct/lambda codegen,
//       which the compiler refused to keep in registers).
// Tail: row = 1000 floats = 250 float4; chunk k=3 valid lanes<58 only.
// Lanes >=58 read float4 index 0 (always in-bounds), inputs zeroed at
// consume: exp(0)-1 == 0 contributes nothing to any sum.

#define N_ROWS  65536
#define N_C     1000
#define NBLOCKS 2048
#define WPB     4

__global__ __launch_bounds__(256) void div2_stage1(
        const float* __restrict__ o1, const float* __restrict__ o2,
        double* __restrict__ ws) {
    const int wave = threadIdx.x >> 6;
    const int lane = threadIdx.x & 63;
    const int gw   = blockIdx.x * WPB + wave;
    const int nw   = NBLOCKS * WPB;
    const int i3   = (lane < 58) ? (192 + lane) : 0;   // clamped chunk-3 idx
    constexpr float INV_T = 1.0f / 20.0f;

    double acc = 0.0;
    #pragma unroll 1
    for (long row = gw; row < (long)N_ROWS; row += nw) {
        const float4* A = reinterpret_cast<const float4*>(o1 + row * (long)N_C);
        const float4* B = reinterpret_cast<const float4*>(o2 + row * (long)N_C);
        // all 8 loads of the row-pair issued before any use
        float4 a0 = A[lane];
        float4 a1 = A[64 + lane];
        float4 a2 = A[128 + lane];
        float4 a3 = A[i3];
        float4 b0 = B[lane];
        float4 b1 = B[64 + lane];
        float4 b2 = B[128 + lane];
        float4 b3 = B[i3];

        float sx = 0.f, sy = 0.f, sxx = 0.f, syy = 0.f, sxy = 0.f;
        float va[16] = {a0.x, a0.y, a0.z, a0.w, a1.x, a1.y, a1.z, a1.w,
                        a2.x, a2.y, a2.z, a2.w, a3.x, a3.y, a3.z, a3.w};
        float vb[16] = {b0.x, b0.y, b0.z, b0.w, b1.x, b1.y, b1.z, b1.w,
                        b2.x, b2.y, b2.z, b2.w, b3.x, b3.y, b3.z, b3.w};
        const bool tail_ok = (lane < 58);
        #pragma unroll
        for (int e = 0; e < 16; ++e) {
            const bool ok = (e < 12) || tail_ok;     // compile-time e
            float fa = ok ? va[e] : 0.0f;            // static index (rule #20)
            float fb = ok ? vb[e] : 0.0f;
            float x = __expf(fa * INV_T) - 1.0f;
            float y = __expf(fb * INV_T) - 1.0f;
            sx += x;  sy += y;
            sxx = fmaf(x, x, sxx);
            syy = fmaf(y, y, syy);
            sxy = fmaf(x, y, sxy);
        }
        #pragma unroll
        for (int off = 32; off; off >>= 1) {
            sx  += __shfl_xor(sx,  off, 64);
            sy  += __shfl_xor(sy,  off, 64);
            sxx += __shfl_xor(sxx, off, 64);
            syy += __shfl_xor(syy, off, 64);
            sxy += __shfl_xor(sxy, off, 64);
        }
        constexpr double invC = 1.0 / (double)N_C;
        double dx = (double)sx, dy = (double)sy;
        double num = (double)sxy - dx * dy * invC;
        double vx  = (double)sxx - dx * dx * invC;
        double vy  = (double)syy - dy * dy * invC;
        acc += num / sqrt(vx * vy);
    }

    __shared__ double dred[WPB];
    if (lane == 0) dred[wave] = acc;
    __syncthreads();
    if (threadIdx.x == 0)
        ws[blockIdx.x] = dred[0] + dred[1] + dred[2] + dred[3];
}

__global__ __launch_bounds__(256) void div2_stage2(
        const double* __restrict__ ws, int n, float* __restrict__ out) {
    double s = 0.0;
    for (int i = threadIdx.x; i < n; i += 256) s += ws[i];
    #pragma unroll
    for (int off = 32; off; off >>= 1) s += __shfl_xor(s, off, 64);
    __shared__ double lds[4];
    const int wave = threadIdx.x >> 6;
    const int lane = threadIdx.x & 63;
    if (lane == 0) lds[wave] = s;
    __syncthreads();
    if (threadIdx.x == 0) {
        double t = lds[0] + lds[1] + lds[2] + lds[3];
        out[0] = (float)(t * (0.3 / (double)N_ROWS));
    }
}

extern "C" void kernel_launch(void* const* d_in, const int* in_sizes, int n_in,
                              void* d_out, int out_size, void* d_ws, size_t ws_size,
                              hipStream_t stream) {
    const float* o1 = (const float*)d_in[0];
    const float* o2 = (const float*)d_in[1];
    // d_in[2] (targets) is unused by the reference.
    float* out = (float*)d_out;
    double* ws = (double*)d_ws;   // 2048 doubles = 16 KB

    div2_stage1<<<NBLOCKS, 256, 0, stream>>>(o1, o2, ws);
    div2_stage2<<<1, 256, 0, stream>>>(ws, NBLOCKS, out);
}